// Round 16
// baseline (578.381 us; speedup 1.0000x reference)
//
#include <hip/hip_runtime.h>
#include <float.h>

typedef __attribute__((ext_vector_type(8))) _Float16 f16x8;
typedef __attribute__((ext_vector_type(4))) float f32x4;
typedef unsigned long long u64;
typedef unsigned int u32;
typedef unsigned short u16;

#define NN 32768
#define KK 8192
#define DD 256
#define BM 128
#define BN 128
#define CSPLIT 4
#define NG 128          // 64-code groups

// ---- ws byte offsets (fast path) = 29,556,736 B (proven footprint) ----
#define WB_ENORM   0
#define WB_XNORM   (WB_ENORM + KK*4)
#define WB_EFP     (WB_XNORM + NN*4)
#define WB_ET      (WB_EFP + KK*DD*2)
#define WB_LOSSP   (WB_ET + (size_t)KK*DD*4)   // first 8B: loss_acc | ticket
#define WB_PART    (WB_LOSSP + (NN/4)*4)
#define WB_NEED    ((size_t)WB_PART + (size_t)NN*NG*4)

// ---- fallback (round-1 validated) ws float offsets ----
#define FCSPLIT 4
#define WSF_ENORM 0
#define WSF_XNORM (KK)
#define WSF_CANDV (KK + NN)
#define WSF_CANDI (KK + NN + NN*FCSPLIT)
#define WSF_LOSS  (KK + NN + 2*NN*FCSPLIT)

__device__ inline void gload16(const void* g, void* l) {
  __builtin_amdgcn_global_load_lds(
      (const __attribute__((address_space(1))) u32*)g,
      (__attribute__((address_space(3))) u32*)l, 16, 0, 0);
}

// d2 in (128, 384); monotone clamped encode, units of 1/256.
__device__ inline u32 enc_d2(float d2) {
  int e = (int)((d2 - 128.f) * 256.f);
  e = e < 0 ? 0 : e;
  e = e > 65535 ? 65535 : e;
  return (u32)e;
}

// ---------------- fused pack (+norms) for BOTH x and emb ----------------
// Block-uniform branch selects source; per-row arithmetic/addresses identical
// to the validated split kernels. x stored as f16(-2x) = -2*f16(x) exactly
// (power-of-2 scale commutes with RTNE); f32 MFMA accumulation is scale-
// invariant under x2, so epilogue (acc+xx)+en == validated fmaf(-2,acc,xx)+en.
__global__ __launch_bounds__(256) void vq_pack_all(const float* __restrict__ x,
                                                   const float* __restrict__ emb,
                                                   u16* __restrict__ xf, u16* __restrict__ ef,
                                                   float* __restrict__ xnorm,
                                                   float* __restrict__ enorm,
                                                   float* __restrict__ loss_acc,
                                                   u32* __restrict__ ticket) {
  __shared__ u16 t[64][264];
  const int b = blockIdx.x;
  const int tid = threadIdx.x;
  const int lane = tid & 63, wid = tid >> 6;
  if (b == 0 && tid == 0) { *loss_acc = 0.f; *ticket = 0u; }  // pre-post zeroing

  const float* src;
  u16* dst;
  float* norm;
  float scale;
  int NR, r0;
  if (b < NN / 64) {
    src = x; dst = xf; norm = xnorm; scale = -2.f; NR = NN; r0 = b * 64;
  } else {
    src = emb; dst = ef; norm = enorm; scale = 1.f; NR = KK; r0 = (b - NN / 64) * 64;
  }

#pragma unroll
  for (int it = 0; it < 16; ++it) {
    int rl = it * 4 + wid;
    float4 v = *(const float4*)(src + (size_t)(r0 + rl) * DD + lane * 4);
    _Float16 a = (_Float16)(v.x * scale), bb = (_Float16)(v.y * scale);
    _Float16 c = (_Float16)(v.z * scale), d = (_Float16)(v.w * scale);
    t[rl][lane * 4 + 0] = *(const u16*)&a;
    t[rl][lane * 4 + 1] = *(const u16*)&bb;
    t[rl][lane * 4 + 2] = *(const u16*)&c;
    t[rl][lane * 4 + 3] = *(const u16*)&d;
    float s = v.x * v.x + v.y * v.y + v.z * v.z + v.w * v.w;
#pragma unroll
    for (int off = 32; off > 0; off >>= 1) s += __shfl_down(s, off, 64);
    if (lane == 0) norm[r0 + rl] = s;
  }
  __syncthreads();
#pragma unroll
  for (int it = 0; it < 8; ++it) {
    int u = it * 256 + tid;
    int d8 = u >> 6, rl = u & 63;
    uint4 w = *(const uint4*)&t[rl][d8 * 8];
    *(uint4*)(dst + ((size_t)d8 * NR + r0 + rl) * 8) = w;
  }
}

// ---------------- blocked transpose: embT4[d/4][k] = emb[k][4d..4d+3] ----------------
__global__ __launch_bounds__(256) void vq_trans(const float* __restrict__ emb,
                                                float4* __restrict__ embT4) {
  __shared__ float t[64][65];
  const int r0 = blockIdx.x * 64;
  const int d0 = blockIdx.y * 64;
  const int tid = threadIdx.x;
#pragma unroll
  for (int i = 0; i < 4; ++i) {
    int flat = i * 256 + tid;
    int rr = flat >> 4, c4 = flat & 15;
    float4 v = *(const float4*)(emb + (size_t)(r0 + rr) * DD + d0 + c4 * 4);
    t[rr][c4 * 4 + 0] = v.x; t[rr][c4 * 4 + 1] = v.y;
    t[rr][c4 * 4 + 2] = v.z; t[rr][c4 * 4 + 3] = v.w;
  }
  __syncthreads();
#pragma unroll
  for (int i = 0; i < 4; ++i) {
    int flat = i * 256 + tid;
    int k = flat & 63, jb = flat >> 6;
    float4 v = {t[k][jb * 4 + 0], t[k][jb * 4 + 1], t[k][jb * 4 + 2], t[k][jb * 4 + 3]};
    embT4[(size_t)(d0 / 4 + jb) * KK + r0 + k] = v;
  }
}

// ---------------- main MFMA screening kernel (R15 exact, validated 269us) ----------------
__global__ __launch_bounds__(256, 4) void vq_mfma(const u16* __restrict__ xf_p,
                                                  const u16* __restrict__ ef_p,
                                                  const float* __restrict__ xnorm,
                                                  const float* __restrict__ enorm,
                                                  u32* __restrict__ part) {
  __shared__ u16 lds[2][1024][8];  // 32 KB (buf0 reused as u32 slab at end)
  const int tid = threadIdx.x;
  const int lane = tid & 63;
  const int wid = tid >> 6;
  const int wr = wid >> 1, wc = wid & 1;
  const int r0 = blockIdx.x * BM;
  const int cbase = blockIdx.y * (KK / CSPLIT);
  const int u_ = lane >> 4, t_ = lane & 15;

  float xr[4][4];
#pragma unroll
  for (int mf = 0; mf < 4; ++mf)
#pragma unroll
    for (int q = 0; q < 4; ++q) xr[mf][q] = xnorm[r0 + wr * 64 + mf * 16 + u_ * 4 + q];

  const char* gp[4];
  int sd[4], bd[4];
  u32 lf[4];
#pragma unroll
  for (int i = 0; i < 4; ++i) {
    const int f = wid * 256 + i * 64 + lane;
    const int plane = f >> 9, kgrp = (f >> 7) & 3, row = f & 127;
    lf[i] = (u32)f * 16u;
    if (plane) {
      gp[i] = (const char*)ef_p + ((size_t)kgrp * KK + cbase + row) * 16;
      sd[i] = 64 * KK;
      bd[i] = -28 * KK * 16 + 128 * 16;
    } else {
      gp[i] = (const char*)xf_p + ((size_t)kgrp * NN + r0 + row) * 16;
      sd[i] = 64 * NN;
      bd[i] = -28 * NN * 16;
    }
  }
  char* lds0 = (char*)&lds[0][0][0];

  f32x4 acc[4][4];
  u32 pres[4][4];  // per-thread part results: lane t_ holds ct == t_
#pragma unroll
  for (int i = 0; i < 4; ++i)
#pragma unroll
    for (int j = 0; j < 4; ++j) {
      acc[i][j] = (f32x4){0.f, 0.f, 0.f, 0.f};
      pres[i][j] = 0u;
    }

#pragma unroll
  for (int i = 0; i < 4; ++i) gload16(gp[i], lds0 + lf[i]);
#pragma unroll
  for (int i = 0; i < 4; ++i) gp[i] += sd[i];
  __syncthreads();
  int cur = 0;

  for (int step = 0; step < 128; ++step) {
    const int ct = step >> 3, kc = step & 7;
    if (step + 1 < 128) {
      const int nbuf = cur ^ 1;
#pragma unroll
      for (int i = 0; i < 4; ++i) gload16(gp[i], lds0 + (nbuf << 14) + lf[i]);
      const bool bnd = ((step + 2) & 7) == 0;
#pragma unroll
      for (int i = 0; i < 4; ++i) gp[i] += bnd ? bd[i] : sd[i];
    }

    f16x8 bh[4];
#pragma unroll
    for (int nf = 0; nf < 4; ++nf)
      bh[nf] = *(const f16x8*)&lds[cur][512 + u_ * 128 + wc * 64 + nf * 16 + t_][0];
#pragma unroll
    for (int mf = 0; mf < 4; ++mf) {
      f16x8 ah = *(const f16x8*)&lds[cur][u_ * 128 + wr * 64 + mf * 16 + t_][0];
#pragma unroll
      for (int nf = 0; nf < 4; ++nf)
        acc[mf][nf] = __builtin_amdgcn_mfma_f32_16x16x32_f16(ah, bh[nf], acc[mf][nf], 0, 0, 0);
    }

    if (kc == 7) {  // epilogue: per-64-group top-2 via u32-packed tournament
      const int gbase = cbase + ct * BN + wc * 64;
      float en[4];
#pragma unroll
      for (int nf = 0; nf < 4; ++nf) en[nf] = enorm[gbase + nf * 16 + t_];
      const bool keep = (t_ == ct);
#pragma unroll
      for (int mf = 0; mf < 4; ++mf) {
#pragma unroll
        for (int q = 0; q < 4; ++q) {
          const float xx = xr[mf][q];
          u32 w[4];
#pragma unroll
          for (int nf = 0; nf < 4; ++nf) {
            float dd = (acc[mf][nf][q] + xx) + en[nf];
            w[nf] = (__float_as_uint(dd) & 0xFFFFFFC0u) | (u32)(nf * 16 + t_);
          }
          u32 a = min(w[0], w[1]), b = max(w[0], w[1]);
          u32 c = min(w[2], w[3]), d = max(w[2], w[3]);
          u32 m1 = min(a, c);
          u32 m2 = min(min(b, d), max(a, c));
#pragma unroll
          for (int off = 1; off < 16; off <<= 1) {
            u32 o1 = (u32)__shfl_xor((int)m1, off, 64);
            u32 o2 = (u32)__shfl_xor((int)m2, off, 64);
            m2 = min(min(m2, o2), max(m1, o1));
            m1 = min(m1, o1);
          }
          u32 e1 = enc_d2(__uint_as_float(m1 & 0xFFFFFFC0u));
          u32 e2 = enc_d2(__uint_as_float(m2 & 0xFFFFFFC0u));
          u32 delta = e2 - e1;
          if (delta > 7u) delta = 7u;
          u32 code13 = (u32)(gbase + (int)(m1 & 0x3Fu)) & 0x1FFFu;
          u32 pk = (e1 << 16) | (delta << 13) | code13;
          if (keep) pres[mf][q] = pk;
        }
#pragma unroll
        for (int nf = 0; nf < 4; ++nf) acc[mf][nf] = (f32x4){0.f, 0.f, 0.f, 0.f};
      }
    }
    __syncthreads();
    cur ^= 1;
  }

  // post-loop: stash pres to LDS slab, then 1024 fully-coalesced uint4 stores.
  u32* lt = (u32*)lds0;
#pragma unroll
  for (int mf = 0; mf < 4; ++mf)
#pragma unroll
    for (int q = 0; q < 4; ++q) {
      const int rl = wr * 64 + mf * 16 + u_ * 4 + q;
      lt[rl * 36 + 2 * t_ + wc] = pres[mf][q];
    }
  __syncthreads();
  const int g0 = cbase >> 6;
#pragma unroll
  for (int it = 0; it < 4; ++it) {
    const int f = it * 256 + tid;
    const int rl = f >> 3, c4 = f & 7;
    uint4 w4;
    w4.x = lt[rl * 36 + c4 * 4 + 0];
    w4.y = lt[rl * 36 + c4 * 4 + 1];
    w4.z = lt[rl * 36 + c4 * 4 + 2];
    w4.w = lt[rl * 36 + c4 * 4 + 3];
    *(uint4*)&part[(size_t)(r0 + rl) * NG + g0 + c4 * 4] = w4;
  }
}

// ---------------- fused post: select + exact rescore + gather + loss + finalize ----------------
__global__ __launch_bounds__(256) void vq_post(const float* __restrict__ x,
                                               const float* __restrict__ emb,
                                               const float4* __restrict__ embT4,
                                               const float* __restrict__ xnorm,
                                               const float* __restrict__ enorm,
                                               const u32* __restrict__ part,
                                               float* __restrict__ loss_acc,
                                               u32* __restrict__ ticket,
                                               float* __restrict__ out) {
  __shared__ float4 xs[4][64];
  __shared__ u16 slist[4][128];
  __shared__ u16 flist[4][128];
  __shared__ int cnts[4][2];
  __shared__ float lred[4];
  const int tid = threadIdx.x, lane = tid & 63, wid = tid >> 6;
  const int row = blockIdx.x * 4 + wid;
  const float* xrow = x + (size_t)row * DD;

  xs[wid][lane] = ((const float4*)xrow)[lane];
  if (lane == 0) { cnts[wid][0] = 0; cnts[wid][1] = 0; }

  const uint2 pv = ((const uint2*)(part + (size_t)row * NG))[lane];
  int mymin = min((int)(pv.x >> 16), (int)(pv.y >> 16));
#pragma unroll
  for (int off = 1; off < 64; off <<= 1) mymin = min(mymin, __shfl_xor(mymin, off, 64));
  const int thr = mymin + 2;  // provable slack: 0.16 (f16) + 0.49 (mask) + 1 (floor) < 2

  __syncthreads();

#pragma unroll
  for (int h = 0; h < 2; ++h) {
    const u32 v = h ? pv.y : pv.x;
    const int gg = 2 * lane + h;
    const int e1 = (int)(v >> 16);
    const int dl = (int)((v >> 13) & 7u);
    if (e1 + dl <= thr) {
      int p = atomicAdd(&cnts[wid][1], 1);
      flist[wid][p] = (u16)gg;
    } else if (e1 <= thr) {
      int p = atomicAdd(&cnts[wid][0], 1);
      slist[wid][p] = (u16)(v & 0x1FFFu);
    }
  }
  __syncthreads();

  const float xx = xnorm[row];
  u64 best = ~0ull;
  const int nfull = cnts[wid][1], nsing = cnts[wid][0];

  for (int fi = 0; fi < nfull; ++fi) {
    const int code = ((int)flist[wid][fi] << 6) + lane;
    float a = 0.f;
#pragma unroll 8
    for (int db = 0; db < 64; ++db) {
      float4 xv = xs[wid][db];
      float4 ev = embT4[(size_t)db * KK + code];
      a = fmaf(xv.x, ev.x, a);
      a = fmaf(xv.y, ev.y, a);
      a = fmaf(xv.z, ev.z, a);
      a = fmaf(xv.w, ev.w, a);
    }
    float d2 = fmaf(-2.f, a, xx) + enorm[code];
    u64 pk = ((u64)__float_as_uint(d2) << 32) | (u32)code;
    if (pk < best) best = pk;
  }

  for (int base = 0; base < nsing; base += 64) {
    const int idx = base + lane;
    const bool act = idx < nsing;
    const int code = act ? (int)slist[wid][idx] : 0;
    const float* er = emb + (size_t)code * DD;
    float a = 0.f;
#pragma unroll 8
    for (int d4 = 0; d4 < 64; ++d4) {
      float4 xv = xs[wid][d4];
      float4 ev = *(const float4*)(er + d4 * 4);
      a = fmaf(xv.x, ev.x, a);
      a = fmaf(xv.y, ev.y, a);
      a = fmaf(xv.z, ev.z, a);
      a = fmaf(xv.w, ev.w, a);
    }
    float d2 = fmaf(-2.f, a, xx) + enorm[code];
    u64 pk = act ? (((u64)__float_as_uint(d2) << 32) | (u32)code) : ~0ull;
    if (pk < best) best = pk;
  }

#pragma unroll
  for (int off = 1; off < 64; off <<= 1) {
    u64 o = __shfl_xor(best, off, 64);
    if (o < best) best = o;
  }
  const int bi = (int)(u32)(best & 0xFFFFFFFFull);

  if (lane == 0) out[(size_t)NN * DD + 2 + row] = (float)bi;
  float4 qv = ((const float4*)(emb + (size_t)bi * DD))[lane];
  float4 xv = xs[wid][lane];
  float4 st;
  st.x = xv.x + (qv.x - xv.x);
  st.y = xv.y + (qv.y - xv.y);
  st.z = xv.z + (qv.z - xv.z);
  st.w = xv.w + (qv.w - xv.w);
  ((float4*)(out + (size_t)row * DD))[lane] = st;

  float dx = xv.x - qv.x, dy = xv.y - qv.y, dz = xv.z - qv.z, dw = xv.w - qv.w;
  float s2 = dx * dx + dy * dy + dz * dz + dw * dw;
#pragma unroll
  for (int off = 32; off > 0; off >>= 1) s2 += __shfl_down(s2, off, 64);
  if (lane == 0) lred[wid] = s2;
  __syncthreads();
  if (tid == 0) {
    float bsum = lred[0] + lred[1] + lred[2] + lred[3];
    atomicAdd(loss_acc, bsum);           // device-scope (validated R1 pattern)
    __threadfence();
    u32 t = atomicAdd(ticket, 1u);
    if (t == (u32)(gridDim.x - 1)) {     // last block: finalize
      float total = atomicAdd(loss_acc, 0.f);  // coherent read (returns old)
      float loss = total / (float)((size_t)NN * DD);
      out[(size_t)NN * DD] = loss;
      out[(size_t)NN * DD + 1] = loss;
    }
  }
}

// ---------------- fallback path (round-1 validated, f32 VALU) ----------------
__global__ __launch_bounds__(256) void fb_norms(const float* __restrict__ x,
                                                const float* __restrict__ emb,
                                                float* __restrict__ ws) {
  int gid = blockIdx.x * blockDim.x + threadIdx.x;
  int wave = gid >> 6, lane = gid & 63;
  const float* src;
  float* dst;
  if (wave < KK) { src = emb + (size_t)wave * DD; dst = ws + WSF_ENORM + wave; }
  else {
    int r = wave - KK;
    if (r >= NN) return;
    src = x + (size_t)r * DD; dst = ws + WSF_XNORM + r;
  }
  float4 v = ((const float4*)src)[lane];
  float s = v.x * v.x + v.y * v.y + v.z * v.z + v.w * v.w;
#pragma unroll
  for (int off = 32; off > 0; off >>= 1) s += __shfl_down(s, off, 64);
  if (lane == 0) *dst = s;
}

__global__ __launch_bounds__(256) void fb_argmin(const float* __restrict__ x,
                                                 const float* __restrict__ emb,
                                                 float* __restrict__ ws) {
  const float* enorm = ws + WSF_ENORM;
  const float* xnorm = ws + WSF_XNORM;
  float* candv = ws + WSF_CANDV;
  int* candi = (int*)(ws + WSF_CANDI);
  __shared__ float As[32][BM + 4];
  __shared__ float Bs[32][BN + 4];
  const int tid = threadIdx.x;
  const int tr = tid >> 4, tc = tid & 15;
  const int r0 = blockIdx.x * BM;
  const int split = blockIdx.y;
  const int cb = split * (KK / FCSPLIT);
  float xr[8];
  {
    const float4* p = (const float4*)(xnorm + r0 + tr * 8);
    float4 a = p[0], b = p[1];
    xr[0] = a.x; xr[1] = a.y; xr[2] = a.z; xr[3] = a.w;
    xr[4] = b.x; xr[5] = b.y; xr[6] = b.z; xr[7] = b.w;
  }
  float bestv[8];
  int besti[8];
#pragma unroll
  for (int i = 0; i < 8; i++) { bestv[i] = FLT_MAX; besti[i] = 0; }
  for (int ct = 0; ct < (KK / FCSPLIT) / BN; ++ct) {
    const int c0 = cb + ct * BN;
    float acc[8][8];
#pragma unroll
    for (int i = 0; i < 8; i++)
#pragma unroll
      for (int j = 0; j < 8; j++) acc[i][j] = 0.f;
    for (int kc = 0; kc < DD; kc += 32) {
      __syncthreads();
      const int rrow = tid >> 3, dg = tid & 7;
#pragma unroll
      for (int p = 0; p < 4; ++p) {
        int rw = p * 32 + rrow;
        float4 av = ((const float4*)(x + (size_t)(r0 + rw) * DD + kc))[dg];
        float4 bv = ((const float4*)(emb + (size_t)(c0 + rw) * DD + kc))[dg];
        As[dg * 4 + 0][rw] = av.x; As[dg * 4 + 1][rw] = av.y;
        As[dg * 4 + 2][rw] = av.z; As[dg * 4 + 3][rw] = av.w;
        Bs[dg * 4 + 0][rw] = bv.x; Bs[dg * 4 + 1][rw] = bv.y;
        Bs[dg * 4 + 2][rw] = bv.z; Bs[dg * 4 + 3][rw] = bv.w;
      }
      __syncthreads();
#pragma unroll 4
      for (int kk = 0; kk < 32; ++kk) {
        float4 a0 = *(const float4*)&As[kk][tr * 8];
        float4 a1 = *(const float4*)&As[kk][tr * 8 + 4];
        float4 b0 = *(const float4*)&Bs[kk][tc * 8];
        float4 b1 = *(const float4*)&Bs[kk][tc * 8 + 4];
        float a[8] = {a0.x, a0.y, a0.z, a0.w, a1.x, a1.y, a1.z, a1.w};
        float b[8] = {b0.x, b0.y, b0.z, b0.w, b1.x, b1.y, b1.z, b1.w};
#pragma unroll
        for (int i = 0; i < 8; i++)
#pragma unroll
          for (int j = 0; j < 8; j++) acc[i][j] = fmaf(a[i], b[j], acc[i][j]);
      }
    }
    float en[8];
    {
      const float4* p = (const float4*)(enorm + c0 + tc * 8);
      float4 a = p[0], b = p[1];
      en[0] = a.x; en[1] = a.y; en[2] = a.z; en[3] = a.w;
      en[4] = b.x; en[5] = b.y; en[6] = b.z; en[7] = b.w;
    }
#pragma unroll
    for (int i = 0; i < 8; i++)
#pragma unroll
      for (int j = 0; j < 8; j++) {
        float t = fmaf(-2.f, acc[i][j], xr[i]);
        float d2 = t + en[j];
        int code = c0 + tc * 8 + j;
        if (d2 < bestv[i]) { bestv[i] = d2; besti[i] = code; }
      }
  }
#pragma unroll
  for (int i = 0; i < 8; i++) {
    float v = bestv[i];
    int bi = besti[i];
#pragma unroll
    for (int off = 1; off < 16; off <<= 1) {
      float v2 = __shfl_xor(v, off, 64);
      int i2 = __shfl_xor(bi, off, 64);
      if (v2 < v || (v2 == v && i2 < bi)) { v = v2; bi = i2; }
    }
    if (tc == 0) {
      int row = r0 + tr * 8 + i;
      candv[row * FCSPLIT + split] = v;
      candi[row * FCSPLIT + split] = bi;
    }
  }
}

__global__ __launch_bounds__(256) void fb_gather(const float* __restrict__ x,
                                                 const float* __restrict__ emb,
                                                 float* __restrict__ ws,
                                                 float* __restrict__ out) {
  const float* candv = ws + WSF_CANDV;
  const int* candi = (const int*)(ws + WSF_CANDI);
  float* loss_acc = ws + WSF_LOSS;
  int gid = blockIdx.x * blockDim.x + threadIdx.x;
  int row = gid >> 6, lane = gid & 63;
  if (row >= NN) return;
  float bv = candv[row * FCSPLIT];
  int bi = candi[row * FCSPLIT];
#pragma unroll
  for (int s = 1; s < FCSPLIT; s++) {
    float v = candv[row * FCSPLIT + s];
    int ii = candi[row * FCSPLIT + s];
    if (v < bv || (v == bv && ii < bi)) { bv = v; bi = ii; }
  }
  if (lane == 0) out[(size_t)NN * DD + 2 + row] = (float)bi;
  float4 qv = ((const float4*)(emb + (size_t)bi * DD))[lane];
  float4 xv = ((const float4*)(x + (size_t)row * DD))[lane];
  float4 st;
  st.x = xv.x + (qv.x - xv.x);
  st.y = xv.y + (qv.y - xv.y);
  st.z = xv.z + (qv.z - xv.z);
  st.w = xv.w + (qv.w - xv.w);
  ((float4*)(out + (size_t)row * DD))[lane] = st;
  float dx = xv.x - qv.x, dy = xv.y - qv.y, dz = xv.z - qv.z, dw = xv.w - qv.w;
  float s2 = dx * dx + dy * dy + dz * dz + dw * dw;
#pragma unroll
  for (int off = 32; off > 0; off >>= 1) s2 += __shfl_down(s2, off, 64);
  if (lane == 0) atomicAdd(loss_acc, s2);
}

__global__ void fb_finalize(const float* __restrict__ ws, float* __restrict__ out) {
  float loss = ws[WSF_LOSS] / (float)((size_t)NN * DD);
  out[(size_t)NN * DD] = loss;
  out[(size_t)NN * DD + 1] = loss;
}

// ---------------- launch ----------------
extern "C" void kernel_launch(void* const* d_in, const int* in_sizes, int n_in,
                              void* d_out, int out_size, void* d_ws, size_t ws_size,
                              hipStream_t stream) {
  const float* x = (const float*)d_in[0];
  const float* emb = (const float*)d_in[1];
  float* out = (float*)d_out;
  char* ws = (char*)d_ws;

  if (ws_size >= WB_NEED) {
    float* xnorm = (float*)(ws + WB_XNORM);
    float* enorm = (float*)(ws + WB_ENORM);
    u16* ef_p = (u16*)(ws + WB_EFP);
    float4* embT4 = (float4*)(ws + WB_ET);
    float* loss_acc = (float*)(ws + WB_LOSSP);
    u32* ticket = (u32*)(ws + WB_LOSSP + 4);
    u32* part = (u32*)(ws + WB_PART);
    // packed x f16 plane lives in d_out's quantized region (16 MB of 33.7 MB);
    // written by pack, read by mfma, overwritten by post — stream-ordered.
    u16* xf_p = (u16*)out;

    vq_pack_all<<<(NN + KK) / 64, 256, 0, stream>>>(x, emb, xf_p, ef_p, xnorm, enorm,
                                                    loss_acc, ticket);
    vq_trans<<<dim3(KK / 64, DD / 64), 256, 0, stream>>>(emb, embT4);
    vq_mfma<<<dim3(NN / BM, CSPLIT), 256, 0, stream>>>(xf_p, ef_p, xnorm, enorm, part);
    vq_post<<<NN / 4, 256, 0, stream>>>(x, emb, embT4, xnorm, enorm, part,
                                        loss_acc, ticket, out);
  } else {
    float* wsf = (float*)d_ws;
    hipMemsetAsync(ws + (size_t)WSF_LOSS * 4, 0, 4, stream);
    fb_norms<<<((KK + NN) * 64) / 256, 256, 0, stream>>>(x, emb, wsf);
    fb_argmin<<<dim3(NN / BM, FCSPLIT), 256, 0, stream>>>(x, emb, wsf);
    fb_gather<<<(NN * 64) / 256, 256, 0, stream>>>(x, emb, wsf, out);
    fb_finalize<<<1, 1, 0, stream>>>(wsf, out);
  }
}

// Round 17
// 346.541 us; speedup vs baseline: 1.6690x; 1.6690x over previous
//
#include <hip/hip_runtime.h>
#include <float.h>

typedef __attribute__((ext_vector_type(8))) _Float16 f16x8;
typedef __attribute__((ext_vector_type(4))) float f32x4;
typedef unsigned long long u64;
typedef unsigned int u32;
typedef unsigned short u16;

#define NN 32768
#define KK 8192
#define DD 256
#define BM 128
#define BN 128
#define CSPLIT 4
#define NG 128          // 64-code groups

// ---- ws byte offsets (fast path) = 29,556,736 B (proven footprint) ----
#define WB_ENORM   0
#define WB_XNORM   (WB_ENORM + KK*4)
#define WB_EFP     (WB_XNORM + NN*4)
#define WB_ET      (WB_EFP + KK*DD*2)
#define WB_LOSSP   (WB_ET + (size_t)KK*DD*4)
#define WB_PART    (WB_LOSSP + (NN/4)*4)
#define WB_NEED    ((size_t)WB_PART + (size_t)NN*NG*4)

// ---- fallback (round-1 validated) ws float offsets ----
#define FCSPLIT 4
#define WSF_ENORM 0
#define WSF_XNORM (KK)
#define WSF_CANDV (KK + NN)
#define WSF_CANDI (KK + NN + NN*FCSPLIT)
#define WSF_LOSS  (KK + NN + 2*NN*FCSPLIT)

__device__ inline void gload16(const void* g, void* l) {
  __builtin_amdgcn_global_load_lds(
      (const __attribute__((address_space(1))) u32*)g,
      (__attribute__((address_space(3))) u32*)l, 16, 0, 0);
}

// d2 in (128, 384); monotone clamped encode, units of 1/256.
__device__ inline u32 enc_d2(float d2) {
  int e = (int)((d2 - 128.f) * 256.f);
  e = e < 0 ? 0 : e;
  e = e > 65535 ? 65535 : e;
  return (u32)e;
}

// ---------------- fused pack (+norms) for BOTH x and emb ----------------
// Block-uniform branch selects source; per-row arithmetic/addresses identical
// to the validated split kernels. x stored as f16(-2x) = -2*f16(x) exactly
// (power-of-2 scale commutes with RTNE); f32 MFMA accumulation is scale-
// invariant under x2, so epilogue (acc+xx)+en == validated fmaf(-2,acc,xx)+en.
// NOTE R16 lesson: the fused-finalize __threadfence() per post-block flushed
// L2 8192x (post 50->335us). Loss path reverted to R15 losspart+finalize.
__global__ __launch_bounds__(256) void vq_pack_all(const float* __restrict__ x,
                                                   const float* __restrict__ emb,
                                                   u16* __restrict__ xf, u16* __restrict__ ef,
                                                   float* __restrict__ xnorm,
                                                   float* __restrict__ enorm) {
  __shared__ u16 t[64][264];
  const int b = blockIdx.x;
  const int tid = threadIdx.x;
  const int lane = tid & 63, wid = tid >> 6;

  const float* src;
  u16* dst;
  float* norm;
  float scale;
  int NR, r0;
  if (b < NN / 64) {
    src = x; dst = xf; norm = xnorm; scale = -2.f; NR = NN; r0 = b * 64;
  } else {
    src = emb; dst = ef; norm = enorm; scale = 1.f; NR = KK; r0 = (b - NN / 64) * 64;
  }

#pragma unroll
  for (int it = 0; it < 16; ++it) {
    int rl = it * 4 + wid;
    float4 v = *(const float4*)(src + (size_t)(r0 + rl) * DD + lane * 4);
    _Float16 a = (_Float16)(v.x * scale), bb = (_Float16)(v.y * scale);
    _Float16 c = (_Float16)(v.z * scale), d = (_Float16)(v.w * scale);
    t[rl][lane * 4 + 0] = *(const u16*)&a;
    t[rl][lane * 4 + 1] = *(const u16*)&bb;
    t[rl][lane * 4 + 2] = *(const u16*)&c;
    t[rl][lane * 4 + 3] = *(const u16*)&d;
    float s = v.x * v.x + v.y * v.y + v.z * v.z + v.w * v.w;
#pragma unroll
    for (int off = 32; off > 0; off >>= 1) s += __shfl_down(s, off, 64);
    if (lane == 0) norm[r0 + rl] = s;
  }
  __syncthreads();
#pragma unroll
  for (int it = 0; it < 8; ++it) {
    int u = it * 256 + tid;
    int d8 = u >> 6, rl = u & 63;
    uint4 w = *(const uint4*)&t[rl][d8 * 8];
    *(uint4*)(dst + ((size_t)d8 * NR + r0 + rl) * 8) = w;
  }
}

// ---------------- blocked transpose: embT4[d/4][k] = emb[k][4d..4d+3] ----------------
__global__ __launch_bounds__(256) void vq_trans(const float* __restrict__ emb,
                                                float4* __restrict__ embT4) {
  __shared__ float t[64][65];
  const int r0 = blockIdx.x * 64;
  const int d0 = blockIdx.y * 64;
  const int tid = threadIdx.x;
#pragma unroll
  for (int i = 0; i < 4; ++i) {
    int flat = i * 256 + tid;
    int rr = flat >> 4, c4 = flat & 15;
    float4 v = *(const float4*)(emb + (size_t)(r0 + rr) * DD + d0 + c4 * 4);
    t[rr][c4 * 4 + 0] = v.x; t[rr][c4 * 4 + 1] = v.y;
    t[rr][c4 * 4 + 2] = v.z; t[rr][c4 * 4 + 3] = v.w;
  }
  __syncthreads();
#pragma unroll
  for (int i = 0; i < 4; ++i) {
    int flat = i * 256 + tid;
    int k = flat & 63, jb = flat >> 6;
    float4 v = {t[k][jb * 4 + 0], t[k][jb * 4 + 1], t[k][jb * 4 + 2], t[k][jb * 4 + 3]};
    embT4[(size_t)(d0 / 4 + jb) * KK + r0 + k] = v;
  }
}

// ---------------- main MFMA screening kernel (R15 exact, validated 269us) ----------------
__global__ __launch_bounds__(256, 4) void vq_mfma(const u16* __restrict__ xf_p,
                                                  const u16* __restrict__ ef_p,
                                                  const float* __restrict__ xnorm,
                                                  const float* __restrict__ enorm,
                                                  u32* __restrict__ part) {
  __shared__ u16 lds[2][1024][8];  // 32 KB (buf0 reused as u32 slab at end)
  const int tid = threadIdx.x;
  const int lane = tid & 63;
  const int wid = tid >> 6;
  const int wr = wid >> 1, wc = wid & 1;
  const int r0 = blockIdx.x * BM;
  const int cbase = blockIdx.y * (KK / CSPLIT);
  const int u_ = lane >> 4, t_ = lane & 15;

  float xr[4][4];
#pragma unroll
  for (int mf = 0; mf < 4; ++mf)
#pragma unroll
    for (int q = 0; q < 4; ++q) xr[mf][q] = xnorm[r0 + wr * 64 + mf * 16 + u_ * 4 + q];

  const char* gp[4];
  int sd[4], bd[4];
  u32 lf[4];
#pragma unroll
  for (int i = 0; i < 4; ++i) {
    const int f = wid * 256 + i * 64 + lane;
    const int plane = f >> 9, kgrp = (f >> 7) & 3, row = f & 127;
    lf[i] = (u32)f * 16u;
    if (plane) {
      gp[i] = (const char*)ef_p + ((size_t)kgrp * KK + cbase + row) * 16;
      sd[i] = 64 * KK;
      bd[i] = -28 * KK * 16 + 128 * 16;
    } else {
      gp[i] = (const char*)xf_p + ((size_t)kgrp * NN + r0 + row) * 16;
      sd[i] = 64 * NN;
      bd[i] = -28 * NN * 16;
    }
  }
  char* lds0 = (char*)&lds[0][0][0];

  f32x4 acc[4][4];
  u32 pres[4][4];  // per-thread part results: lane t_ holds ct == t_
#pragma unroll
  for (int i = 0; i < 4; ++i)
#pragma unroll
    for (int j = 0; j < 4; ++j) {
      acc[i][j] = (f32x4){0.f, 0.f, 0.f, 0.f};
      pres[i][j] = 0u;
    }

#pragma unroll
  for (int i = 0; i < 4; ++i) gload16(gp[i], lds0 + lf[i]);
#pragma unroll
  for (int i = 0; i < 4; ++i) gp[i] += sd[i];
  __syncthreads();
  int cur = 0;

  for (int step = 0; step < 128; ++step) {
    const int ct = step >> 3, kc = step & 7;
    if (step + 1 < 128) {
      const int nbuf = cur ^ 1;
#pragma unroll
      for (int i = 0; i < 4; ++i) gload16(gp[i], lds0 + (nbuf << 14) + lf[i]);
      const bool bnd = ((step + 2) & 7) == 0;
#pragma unroll
      for (int i = 0; i < 4; ++i) gp[i] += bnd ? bd[i] : sd[i];
    }

    f16x8 bh[4];
#pragma unroll
    for (int nf = 0; nf < 4; ++nf)
      bh[nf] = *(const f16x8*)&lds[cur][512 + u_ * 128 + wc * 64 + nf * 16 + t_][0];
#pragma unroll
    for (int mf = 0; mf < 4; ++mf) {
      f16x8 ah = *(const f16x8*)&lds[cur][u_ * 128 + wr * 64 + mf * 16 + t_][0];
#pragma unroll
      for (int nf = 0; nf < 4; ++nf)
        acc[mf][nf] = __builtin_amdgcn_mfma_f32_16x16x32_f16(ah, bh[nf], acc[mf][nf], 0, 0, 0);
    }

    if (kc == 7) {  // epilogue: per-64-group top-2 via u32-packed tournament
      const int gbase = cbase + ct * BN + wc * 64;
      float en[4];
#pragma unroll
      for (int nf = 0; nf < 4; ++nf) en[nf] = enorm[gbase + nf * 16 + t_];
      const bool keep = (t_ == ct);
#pragma unroll
      for (int mf = 0; mf < 4; ++mf) {
#pragma unroll
        for (int q = 0; q < 4; ++q) {
          const float xx = xr[mf][q];
          u32 w[4];
#pragma unroll
          for (int nf = 0; nf < 4; ++nf) {
            float dd = (acc[mf][nf][q] + xx) + en[nf];
            w[nf] = (__float_as_uint(dd) & 0xFFFFFFC0u) | (u32)(nf * 16 + t_);
          }
          u32 a = min(w[0], w[1]), b = max(w[0], w[1]);
          u32 c = min(w[2], w[3]), d = max(w[2], w[3]);
          u32 m1 = min(a, c);
          u32 m2 = min(min(b, d), max(a, c));
#pragma unroll
          for (int off = 1; off < 16; off <<= 1) {
            u32 o1 = (u32)__shfl_xor((int)m1, off, 64);
            u32 o2 = (u32)__shfl_xor((int)m2, off, 64);
            m2 = min(min(m2, o2), max(m1, o1));
            m1 = min(m1, o1);
          }
          u32 e1 = enc_d2(__uint_as_float(m1 & 0xFFFFFFC0u));
          u32 e2 = enc_d2(__uint_as_float(m2 & 0xFFFFFFC0u));
          u32 delta = e2 - e1;
          if (delta > 7u) delta = 7u;
          u32 code13 = (u32)(gbase + (int)(m1 & 0x3Fu)) & 0x1FFFu;
          u32 pk = (e1 << 16) | (delta << 13) | code13;
          if (keep) pres[mf][q] = pk;
        }
#pragma unroll
        for (int nf = 0; nf < 4; ++nf) acc[mf][nf] = (f32x4){0.f, 0.f, 0.f, 0.f};
      }
    }
    __syncthreads();
    cur ^= 1;
  }

  // post-loop: stash pres to LDS slab, then 1024 fully-coalesced uint4 stores.
  u32* lt = (u32*)lds0;
#pragma unroll
  for (int mf = 0; mf < 4; ++mf)
#pragma unroll
    for (int q = 0; q < 4; ++q) {
      const int rl = wr * 64 + mf * 16 + u_ * 4 + q;
      lt[rl * 36 + 2 * t_ + wc] = pres[mf][q];
    }
  __syncthreads();
  const int g0 = cbase >> 6;
#pragma unroll
  for (int it = 0; it < 4; ++it) {
    const int f = it * 256 + tid;
    const int rl = f >> 3, c4 = f & 7;
    uint4 w4;
    w4.x = lt[rl * 36 + c4 * 4 + 0];
    w4.y = lt[rl * 36 + c4 * 4 + 1];
    w4.z = lt[rl * 36 + c4 * 4 + 2];
    w4.w = lt[rl * 36 + c4 * 4 + 3];
    *(uint4*)&part[(size_t)(r0 + rl) * NG + g0 + c4 * 4] = w4;
  }
}

// ---------------- fused post: per-code select + exact rescore (R15 validated) ----------------
__global__ __launch_bounds__(256) void vq_post(const float* __restrict__ x,
                                               const float* __restrict__ emb,
                                               const float4* __restrict__ embT4,
                                               const float* __restrict__ xnorm,
                                               const float* __restrict__ enorm,
                                               const u32* __restrict__ part,
                                               float* __restrict__ losspart,
                                               float* __restrict__ out) {
  __shared__ float4 xs[4][64];
  __shared__ u16 slist[4][128];
  __shared__ u16 flist[4][128];
  __shared__ int cnts[4][2];
  __shared__ float lred[4];
  const int tid = threadIdx.x, lane = tid & 63, wid = tid >> 6;
  const int row = blockIdx.x * 4 + wid;
  const float* xrow = x + (size_t)row * DD;

  xs[wid][lane] = ((const float4*)xrow)[lane];
  if (lane == 0) { cnts[wid][0] = 0; cnts[wid][1] = 0; }

  const uint2 pv = ((const uint2*)(part + (size_t)row * NG))[lane];
  int mymin = min((int)(pv.x >> 16), (int)(pv.y >> 16));
#pragma unroll
  for (int off = 1; off < 64; off <<= 1) mymin = min(mymin, __shfl_xor(mymin, off, 64));
  const int thr = mymin + 2;  // provable slack: 0.16 (f16) + 0.49 (mask) + 1 (floor) < 2

  __syncthreads();

#pragma unroll
  for (int h = 0; h < 2; ++h) {
    const u32 v = h ? pv.y : pv.x;
    const int gg = 2 * lane + h;
    const int e1 = (int)(v >> 16);
    const int dl = (int)((v >> 13) & 7u);
    if (e1 + dl <= thr) {
      int p = atomicAdd(&cnts[wid][1], 1);
      flist[wid][p] = (u16)gg;
    } else if (e1 <= thr) {
      int p = atomicAdd(&cnts[wid][0], 1);
      slist[wid][p] = (u16)(v & 0x1FFFu);
    }
  }
  __syncthreads();

  const float xx = xnorm[row];
  u64 best = ~0ull;
  const int nfull = cnts[wid][1], nsing = cnts[wid][0];

  for (int fi = 0; fi < nfull; ++fi) {
    const int code = ((int)flist[wid][fi] << 6) + lane;
    float a = 0.f;
#pragma unroll 8
    for (int db = 0; db < 64; ++db) {
      float4 xv = xs[wid][db];
      float4 ev = embT4[(size_t)db * KK + code];
      a = fmaf(xv.x, ev.x, a);
      a = fmaf(xv.y, ev.y, a);
      a = fmaf(xv.z, ev.z, a);
      a = fmaf(xv.w, ev.w, a);
    }
    float d2 = fmaf(-2.f, a, xx) + enorm[code];
    u64 pk = ((u64)__float_as_uint(d2) << 32) | (u32)code;
    if (pk < best) best = pk;
  }

  for (int base = 0; base < nsing; base += 64) {
    const int idx = base + lane;
    const bool act = idx < nsing;
    const int code = act ? (int)slist[wid][idx] : 0;
    const float* er = emb + (size_t)code * DD;
    float a = 0.f;
#pragma unroll 8
    for (int d4 = 0; d4 < 64; ++d4) {
      float4 xv = xs[wid][d4];
      float4 ev = *(const float4*)(er + d4 * 4);
      a = fmaf(xv.x, ev.x, a);
      a = fmaf(xv.y, ev.y, a);
      a = fmaf(xv.z, ev.z, a);
      a = fmaf(xv.w, ev.w, a);
    }
    float d2 = fmaf(-2.f, a, xx) + enorm[code];
    u64 pk = act ? (((u64)__float_as_uint(d2) << 32) | (u32)code) : ~0ull;
    if (pk < best) best = pk;
  }

#pragma unroll
  for (int off = 1; off < 64; off <<= 1) {
    u64 o = __shfl_xor(best, off, 64);
    if (o < best) best = o;
  }
  const int bi = (int)(u32)(best & 0xFFFFFFFFull);

  if (lane == 0) out[(size_t)NN * DD + 2 + row] = (float)bi;
  float4 qv = ((const float4*)(emb + (size_t)bi * DD))[lane];
  float4 xv = xs[wid][lane];
  float4 st;
  st.x = xv.x + (qv.x - xv.x);
  st.y = xv.y + (qv.y - xv.y);
  st.z = xv.z + (qv.z - xv.z);
  st.w = xv.w + (qv.w - xv.w);
  ((float4*)(out + (size_t)row * DD))[lane] = st;

  float dx = xv.x - qv.x, dy = xv.y - qv.y, dz = xv.z - qv.z, dw = xv.w - qv.w;
  float s2 = dx * dx + dy * dy + dz * dz + dw * dw;
#pragma unroll
  for (int off = 32; off > 0; off >>= 1) s2 += __shfl_down(s2, off, 64);
  if (lane == 0) lred[wid] = s2;
  __syncthreads();
  if (tid == 0) losspart[blockIdx.x] = lred[0] + lred[1] + lred[2] + lred[3];
}

__global__ __launch_bounds__(256) void vq_finalize(const float* __restrict__ losspart,
                                                   float* __restrict__ out) {
  __shared__ float l[256];
  float s = 0.f;
  for (int i = threadIdx.x; i < NN / 4; i += 256) s += losspart[i];
  l[threadIdx.x] = s;
  __syncthreads();
  for (int o = 128; o > 0; o >>= 1) {
    if (threadIdx.x < o) l[threadIdx.x] += l[threadIdx.x + o];
    __syncthreads();
  }
  if (threadIdx.x == 0) {
    float loss = l[0] / (float)((size_t)NN * DD);
    out[(size_t)NN * DD] = loss;
    out[(size_t)NN * DD + 1] = loss;
  }
}

// ---------------- fallback path (round-1 validated, f32 VALU) ----------------
__global__ __launch_bounds__(256) void fb_norms(const float* __restrict__ x,
                                                const float* __restrict__ emb,
                                                float* __restrict__ ws) {
  int gid = blockIdx.x * blockDim.x + threadIdx.x;
  int wave = gid >> 6, lane = gid & 63;
  const float* src;
  float* dst;
  if (wave < KK) { src = emb + (size_t)wave * DD; dst = ws + WSF_ENORM + wave; }
  else {
    int r = wave - KK;
    if (r >= NN) return;
    src = x + (size_t)r * DD; dst = ws + WSF_XNORM + r;
  }
  float4 v = ((const float4*)src)[lane];
  float s = v.x * v.x + v.y * v.y + v.z * v.z + v.w * v.w;
#pragma unroll
  for (int off = 32; off > 0; off >>= 1) s += __shfl_down(s, off, 64);
  if (lane == 0) *dst = s;
}

__global__ __launch_bounds__(256) void fb_argmin(const float* __restrict__ x,
                                                 const float* __restrict__ emb,
                                                 float* __restrict__ ws) {
  const float* enorm = ws + WSF_ENORM;
  const float* xnorm = ws + WSF_XNORM;
  float* candv = ws + WSF_CANDV;
  int* candi = (int*)(ws + WSF_CANDI);
  __shared__ float As[32][BM + 4];
  __shared__ float Bs[32][BN + 4];
  const int tid = threadIdx.x;
  const int tr = tid >> 4, tc = tid & 15;
  const int r0 = blockIdx.x * BM;
  const int split = blockIdx.y;
  const int cb = split * (KK / FCSPLIT);
  float xr[8];
  {
    const float4* p = (const float4*)(xnorm + r0 + tr * 8);
    float4 a = p[0], b = p[1];
    xr[0] = a.x; xr[1] = a.y; xr[2] = a.z; xr[3] = a.w;
    xr[4] = b.x; xr[5] = b.y; xr[6] = b.z; xr[7] = b.w;
  }
  float bestv[8];
  int besti[8];
#pragma unroll
  for (int i = 0; i < 8; i++) { bestv[i] = FLT_MAX; besti[i] = 0; }
  for (int ct = 0; ct < (KK / FCSPLIT) / BN; ++ct) {
    const int c0 = cb + ct * BN;
    float acc[8][8];
#pragma unroll
    for (int i = 0; i < 8; i++)
#pragma unroll
      for (int j = 0; j < 8; j++) acc[i][j] = 0.f;
    for (int kc = 0; kc < DD; kc += 32) {
      __syncthreads();
      const int rrow = tid >> 3, dg = tid & 7;
#pragma unroll
      for (int p = 0; p < 4; ++p) {
        int rw = p * 32 + rrow;
        float4 av = ((const float4*)(x + (size_t)(r0 + rw) * DD + kc))[dg];
        float4 bv = ((const float4*)(emb + (size_t)(c0 + rw) * DD + kc))[dg];
        As[dg * 4 + 0][rw] = av.x; As[dg * 4 + 1][rw] = av.y;
        As[dg * 4 + 2][rw] = av.z; As[dg * 4 + 3][rw] = av.w;
        Bs[dg * 4 + 0][rw] = bv.x; Bs[dg * 4 + 1][rw] = bv.y;
        Bs[dg * 4 + 2][rw] = bv.z; Bs[dg * 4 + 3][rw] = bv.w;
      }
      __syncthreads();
#pragma unroll 4
      for (int kk = 0; kk < 32; ++kk) {
        float4 a0 = *(const float4*)&As[kk][tr * 8];
        float4 a1 = *(const float4*)&As[kk][tr * 8 + 4];
        float4 b0 = *(const float4*)&Bs[kk][tc * 8];
        float4 b1 = *(const float4*)&Bs[kk][tc * 8 + 4];
        float a[8] = {a0.x, a0.y, a0.z, a0.w, a1.x, a1.y, a1.z, a1.w};
        float b[8] = {b0.x, b0.y, b0.z, b0.w, b1.x, b1.y, b1.z, b1.w};
#pragma unroll
        for (int i = 0; i < 8; i++)
#pragma unroll
          for (int j = 0; j < 8; j++) acc[i][j] = fmaf(a[i], b[j], acc[i][j]);
      }
    }
    float en[8];
    {
      const float4* p = (const float4*)(enorm + c0 + tc * 8);
      float4 a = p[0], b = p[1];
      en[0] = a.x; en[1] = a.y; en[2] = a.z; en[3] = a.w;
      en[4] = b.x; en[5] = b.y; en[6] = b.z; en[7] = b.w;
    }
#pragma unroll
    for (int i = 0; i < 8; i++)
#pragma unroll
      for (int j = 0; j < 8; j++) {
        float t = fmaf(-2.f, acc[i][j], xr[i]);
        float d2 = t + en[j];
        int code = c0 + tc * 8 + j;
        if (d2 < bestv[i]) { bestv[i] = d2; besti[i] = code; }
      }
  }
#pragma unroll
  for (int i = 0; i < 8; i++) {
    float v = bestv[i];
    int bi = besti[i];
#pragma unroll
    for (int off = 1; off < 16; off <<= 1) {
      float v2 = __shfl_xor(v, off, 64);
      int i2 = __shfl_xor(bi, off, 64);
      if (v2 < v || (v2 == v && i2 < bi)) { v = v2; bi = i2; }
    }
    if (tc == 0) {
      int row = r0 + tr * 8 + i;
      candv[row * FCSPLIT + split] = v;
      candi[row * FCSPLIT + split] = bi;
    }
  }
}

__global__ __launch_bounds__(256) void fb_gather(const float* __restrict__ x,
                                                 const float* __restrict__ emb,
                                                 float* __restrict__ ws,
                                                 float* __restrict__ out) {
  const float* candv = ws + WSF_CANDV;
  const int* candi = (const int*)(ws + WSF_CANDI);
  float* loss_acc = ws + WSF_LOSS;
  int gid = blockIdx.x * blockDim.x + threadIdx.x;
  int row = gid >> 6, lane = gid & 63;
  if (row >= NN) return;
  float bv = candv[row * FCSPLIT];
  int bi = candi[row * FCSPLIT];
#pragma unroll
  for (int s = 1; s < FCSPLIT; s++) {
    float v = candv[row * FCSPLIT + s];
    int ii = candi[row * FCSPLIT + s];
    if (v < bv || (v == bv && ii < bi)) { bv = v; bi = ii; }
  }
  if (lane == 0) out[(size_t)NN * DD + 2 + row] = (float)bi;
  float4 qv = ((const float4*)(emb + (size_t)bi * DD))[lane];
  float4 xv = ((const float4*)(x + (size_t)row * DD))[lane];
  float4 st;
  st.x = xv.x + (qv.x - xv.x);
  st.y = xv.y + (qv.y - xv.y);
  st.z = xv.z + (qv.z - xv.z);
  st.w = xv.w + (qv.w - xv.w);
  ((float4*)(out + (size_t)row * DD))[lane] = st;
  float dx = xv.x - qv.x, dy = xv.y - qv.y, dz = xv.z - qv.z, dw = xv.w - qv.w;
  float s2 = dx * dx + dy * dy + dz * dz + dw * dw;
#pragma unroll
  for (int off = 32; off > 0; off >>= 1) s2 += __shfl_down(s2, off, 64);
  if (lane == 0) atomicAdd(loss_acc, s2);
}

__global__ void fb_finalize(const float* __restrict__ ws, float* __restrict__ out) {
  float loss = ws[WSF_LOSS] / (float)((size_t)NN * DD);
  out[(size_t)NN * DD] = loss;
  out[(size_t)NN * DD + 1] = loss;
}

// ---------------- launch ----------------
extern "C" void kernel_launch(void* const* d_in, const int* in_sizes, int n_in,
                              void* d_out, int out_size, void* d_ws, size_t ws_size,
                              hipStream_t stream) {
  const float* x = (const float*)d_in[0];
  const float* emb = (const float*)d_in[1];
  float* out = (float*)d_out;
  char* ws = (char*)d_ws;

  if (ws_size >= WB_NEED) {
    float* xnorm = (float*)(ws + WB_XNORM);
    float* enorm = (float*)(ws + WB_ENORM);
    u16* ef_p = (u16*)(ws + WB_EFP);
    float4* embT4 = (float4*)(ws + WB_ET);
    float* losspart = (float*)(ws + WB_LOSSP);
    u32* part = (u32*)(ws + WB_PART);
    // packed x f16 plane lives in d_out's quantized region (16 MB of 33.7 MB);
    // written by pack, read by mfma, overwritten by post — stream-ordered.
    u16* xf_p = (u16*)out;

    vq_pack_all<<<(NN + KK) / 64, 256, 0, stream>>>(x, emb, xf_p, ef_p, xnorm, enorm);
    vq_trans<<<dim3(KK / 64, DD / 64), 256, 0, stream>>>(emb, embT4);
    vq_mfma<<<dim3(NN / BM, CSPLIT), 256, 0, stream>>>(xf_p, ef_p, xnorm, enorm, part);
    vq_post<<<NN / 4, 256, 0, stream>>>(x, emb, embT4, xnorm, enorm, part, losspart, out);
    vq_finalize<<<1, 256, 0, stream>>>(losspart, out);
  } else {
    float* wsf = (float*)d_ws;
    hipMemsetAsync(ws + (size_t)WSF_LOSS * 4, 0, 4, stream);
    fb_norms<<<((KK + NN) * 64) / 256, 256, 0, stream>>>(x, emb, wsf);
    fb_argmin<<<dim3(NN / BM, FCSPLIT), 256, 0, stream>>>(x, emb, wsf);
    fb_gather<<<(NN * 64) / 256, 256, 0, stream>>>(x, emb, wsf, out);
    fb_finalize<<<1, 1, 0, stream>>>(wsf, out);
  }
}